// Round 17
// baseline (265.285 us; speedup 1.0000x reference)
//
#include <hip/hip_runtime.h>
#include <hip/hip_bf16.h>
#include <stdint.h>
#include <stddef.h>

typedef unsigned short u16;
using bf16x8 = __attribute__((ext_vector_type(8))) short;   // 8 bf16 = 4 VGPR
using f32x4  = __attribute__((ext_vector_type(4))) float;
using f32x16 = __attribute__((ext_vector_type(16))) float;

#define DEVFN static __device__ __forceinline__

DEVFN u16 f2b(float f){ __hip_bfloat16 h = __float2bfloat16(f); return *reinterpret_cast<u16*>(&h); }
DEVFN float b2f(u16 u){ __hip_bfloat16 h; *reinterpret_cast<u16*>(&h) = u; return __bfloat162float(h); }
DEVFN uint32_t pk2(float a, float b){
  uint32_t r; asm("v_cvt_pk_bf16_f32 %0, %1, %2" : "=v"(r) : "v"(a), "v"(b)); return r;
}
DEVFN float ex2(float x){ float r; asm("v_exp_f32 %0, %1" : "=v"(r) : "v"(x)); return r; }

DEVFN void gload_lds16(const void* g, void* l){
  __builtin_amdgcn_global_load_lds(
      (const __attribute__((address_space(1))) void*)g,
      (__attribute__((address_space(3))) void*)l, 16, 0, 0);
}

// ---------------- dtype detect: freqs_cos[0]==1.0f -> f32 (0x3F800000), bf16 pair -> 0x3F803F80
__global__ void detect_k(const uint32_t* __restrict__ fc_raw, uint32_t* __restrict__ flag){
  if (threadIdx.x == 0 && blockIdx.x == 0)
    flag[0] = (fc_raw[0] == 0x3F800000u) ? 1u : 0u;
}

// ---------------- both freq tables -> f32, one launch ----------------
__global__ __launch_bounds__(256) void cvtf2_k(const void* __restrict__ inc, const void* __restrict__ ins,
                                               float* __restrict__ outc, float* __restrict__ outs,
                                               int n, const uint32_t* __restrict__ flag){
  const int i = blockIdx.x*256 + threadIdx.x;
  const bool f32in = flag[0] != 0;
  if (i < n){
    outc[i] = f32in ? ((const float*)inc)[i] : b2f(((const u16*)inc)[i]);
  } else if (i < 2*n){
    const int k = i - n;
    outs[k] = f32in ? ((const float*)ins)[k] : b2f(((const u16*)ins)[k]);
  }
}

// ---------------- x -> bf16 (8 elems/thread) ----------------
__global__ __launch_bounds__(256) void cvtx_k(const void* __restrict__ in, u16* __restrict__ out,
                                              int n8, const uint32_t* __restrict__ flag){
  const int i = blockIdx.x*256 + threadIdx.x;
  if (i >= n8) return;
  __align__(16) u16 e[8];
  if (flag[0]){
    const float* f = (const float*)in + (size_t)i*8;
    float4 a = *(const float4*)f, b = *(const float4*)(f+4);
    e[0]=f2b(a.x); e[1]=f2b(a.y); e[2]=f2b(a.z); e[3]=f2b(a.w);
    e[4]=f2b(b.x); e[5]=f2b(b.y); e[6]=f2b(b.z); e[7]=f2b(b.w);
  } else {
    *(uint4*)e = *((const uint4*)in + i);
  }
  *(uint4*)(out + (size_t)i*8) = *(const uint4*)e;
}

// ---------------- weight transpose (+dtype cvt): in (R x C) -> out bf16 (C x R) ----------------
__global__ __launch_bounds__(512) void wtrans_k(const void* __restrict__ in, u16* __restrict__ out,
                                                int C, int R, const uint32_t* __restrict__ flag){
  __shared__ __align__(16) u16 tile[64][72];
  const int r0 = blockIdx.y*64, c0 = blockIdx.x*64;
  const int t = threadIdx.x, r = t>>3, cs = (t&7)*8;
  __align__(16) u16 e[8];
  if (flag[0]){
    const float* f = (const float*)in + (size_t)(r0+r)*C + c0 + cs;
    float4 a = *(const float4*)f, b = *(const float4*)(f+4);
    e[0]=f2b(a.x); e[1]=f2b(a.y); e[2]=f2b(a.z); e[3]=f2b(a.w);
    e[4]=f2b(b.x); e[5]=f2b(b.y); e[6]=f2b(b.z); e[7]=f2b(b.w);
  } else {
    *(uint4*)e = *(const uint4*)((const u16*)in + (size_t)(r0+r)*C + c0 + cs);
  }
#pragma unroll
  for (int j=0;j<8;j++) tile[cs+j][r] = e[j];
  __syncthreads();
  uint4 o = *(const uint4*)&tile[r][cs];
  *(uint4*)(out + (size_t)(c0+r)*R + r0 + cs) = o;
}

// ---------------- V transpose: qkv v-slice (t x d) -> vT[(b*8+g)*128 + d][t] ----------------
__global__ __launch_bounds__(512) void vtrans_k(const u16* __restrict__ qkv, u16* __restrict__ vT){
  __shared__ __align__(16) u16 tile[64][72];
  const int z = blockIdx.z, b = z>>3, g = z&7;
  const u16* in = qkv + (size_t)(b*2048)*4096 + 3072 + g*128;
  u16* out = vT + (size_t)z*128*2048;
  const int r0 = blockIdx.y*64, c0 = blockIdx.x*64;   // r0 over t, c0 over d
  const int t = threadIdx.x, r = t>>3, cs = (t&7)*8;
  uint4 v = *(const uint4*)(in + (size_t)(r0+r)*4096 + c0 + cs);
  const u16* e = (const u16*)&v;
#pragma unroll
  for (int j=0;j<8;j++) tile[cs+j][r] = e[j];
  __syncthreads();
  uint4 o = *(const uint4*)&tile[r][cs];
  *(uint4*)(out + (size_t)(c0+r)*2048 + r0 + cs) = o;
}

// ---------------- pipelined GEMM v1: BM=256, BN=128 (proj) ----------------
__global__ __launch_bounds__(512) void gemm_p(const u16* __restrict__ A, const u16* __restrict__ Bt,
                                              void* __restrict__ Cv, int M, int N, int K,
                                              const uint32_t* __restrict__ flag, int fin){
  __shared__ __align__(16) u16 L[3*12288];
  const int nwg_x = N>>7;
  int wg = blockIdx.x;
  { const int cpx = (int)gridDim.x >> 3; wg = (wg&7)*cpx + (wg>>3); }
  const int tm = (wg / nwg_x)*256, tn = (wg % nwg_x)*128;
  const int tid = threadIdx.x, w = tid>>6, l = tid&63, lr = l&15, lg = l>>4;
  const int wm = w>>1, wn = w&1;

  f32x4 acc[4][4] = {};

  auto stage = [&](int kt, int buf){
    const int kk = kt*32;
    u16* Lb = &L[buf*12288];
#pragma unroll
    for (int j=0;j<2;j++){
      const int s = j*512 + tid;
      const int row = s>>2, c = s&3;
      const int gch = c ^ ((row ^ (row>>2)) & 3);
      gload_lds16(A + (size_t)(tm + row)*K + kk + gch*8, &Lb[(j*512 + w*64)*8]);
    }
    {
      const int s = tid;
      const int row = s>>2, c = s&3;
      const int gch = c ^ ((row ^ (row>>2)) & 3);
      gload_lds16(Bt + (size_t)(tn + row)*K + kk + gch*8, &Lb[8192 + (w*64)*8]);
    }
  };

  const int nk = K>>5;
  stage(0,0); stage(1,1);
  asm volatile("s_waitcnt vmcnt(3)" ::: "memory");
  __builtin_amdgcn_s_barrier();
  __builtin_amdgcn_sched_barrier(0);

  for (int kt=0; kt<nk; ++kt){
    const int buf = kt % 3;
    if (kt+2 < nk) stage(kt+2, (kt+2) % 3);
    const u16* Ab = &L[buf*12288];
    const u16* Bb = Ab + 8192;
    bf16x8 a[4], b[4];
#pragma unroll
    for (int mi=0;mi<4;mi++){
      const int row = wm*64 + mi*16 + lr;
      a[mi] = *(const bf16x8*)&Ab[row*32 + ((lg ^ ((row ^ (row>>2))&3))*8)];
    }
#pragma unroll
    for (int ni=0;ni<4;ni++){
      const int row = wn*64 + ni*16 + lr;
      b[ni] = *(const bf16x8*)&Bb[row*32 + ((lg ^ ((row ^ (row>>2))&3))*8)];
    }
#pragma unroll
    for (int mi=0;mi<4;mi++)
#pragma unroll
      for (int ni=0;ni<4;ni++)
        acc[mi][ni] = __builtin_amdgcn_mfma_f32_16x16x32_bf16(a[mi], b[ni], acc[mi][ni], 0,0,0);
    __builtin_amdgcn_sched_barrier(0);
    if (kt+2 < nk) asm volatile("s_waitcnt vmcnt(3)" ::: "memory");
    else           asm volatile("s_waitcnt vmcnt(0)" ::: "memory");
    __builtin_amdgcn_s_barrier();
    __builtin_amdgcn_sched_barrier(0);
  }

  const bool of32 = fin && (flag[0] != 0);
#pragma unroll
  for (int mi=0;mi<4;mi++)
#pragma unroll
    for (int ni=0;ni<4;ni++)
#pragma unroll
      for (int reg=0;reg<4;reg++){
        const int row = tm + wm*64 + mi*16 + lg*4 + reg;
        const int col = tn + wn*64 + ni*16 + lr;
        const size_t idx = (size_t)row*N + col;
        const float v = acc[mi][ni][reg];
        if (of32) ((float*)Cv)[idx] = v;
        else      ((u16*)Cv)[idx]   = f2b(v);
      }
}

// ---------------- pipelined GEMM v2q: BM=BN=256, per-wave 128x64, 4-deep, fused RoPE ----------
// Changes vs R16 gemm_p2: (1) 4 LDS buffers (128KB), vmcnt(8) steady-state -> loads
// get 2 iterations to land (HBM-miss ~900cyc > 1 iter). Induction: end of iter j
// waits vmcnt(8) with tiles j+1..j+3 in flight (12 loads) -> tile j+1 landed.
// Drain: 8 -> 4 -> 0. stage(kt+3) targets buf (kt-1)%4, readers retired at kt-1.
// (2) RoPE fused in epilogue: pair (2p,2p+1) = lanes (l, l^1) of same fragment
// (col parity == lr parity; q/k/v boundaries multiples of 16 -> wave-uniform).
// q cols additionally scaled by 1/sqrt(D)*log2(e) (attn runs exp2-domain softmax).
__global__ __launch_bounds__(512) void gemm_q(const u16* __restrict__ A, const u16* __restrict__ Bt,
                                              u16* __restrict__ Cv, int M, int N, int K,
                                              const float* __restrict__ fc, const float* __restrict__ fs){
  __shared__ __align__(16) u16 L[4*16384];
  const int nwg_x = N>>8;
  int wg = blockIdx.x;
  { const int cpx = (int)gridDim.x >> 3; wg = (wg&7)*cpx + (wg>>3); }
  const int tm = (wg / nwg_x)*256, tn = (wg % nwg_x)*256;
  const int tid = threadIdx.x, w = tid>>6, l = tid&63, lr = l&15, lg = l>>4;
  const int wm = w>>2, wn = w&3;

  f32x4 acc[8][4] = {};

  auto stage = [&](int kt, int buf){
    const int kk = kt*32;
    u16* Lb = &L[buf*16384];
#pragma unroll
    for (int j=0;j<2;j++){
      const int s = j*512 + tid;
      const int row = s>>2, c = s&3;
      const int gch = c ^ ((row ^ (row>>2)) & 3);
      gload_lds16(A + (size_t)(tm + row)*K + kk + gch*8, &Lb[(j*512 + w*64)*8]);
    }
#pragma unroll
    for (int j=0;j<2;j++){
      const int s = j*512 + tid;
      const int row = s>>2, c = s&3;
      const int gch = c ^ ((row ^ (row>>2)) & 3);
      gload_lds16(Bt + (size_t)(tn + row)*K + kk + gch*8, &Lb[8192 + (j*512 + w*64)*8]);
    }
  };

  const int nk = K>>5;
  stage(0,0); stage(1,1); stage(2,2);
  asm volatile("s_waitcnt vmcnt(8)" ::: "memory");   // tile0's 4 landed; 1,2 in flight
  __builtin_amdgcn_s_barrier();
  __builtin_amdgcn_sched_barrier(0);

  for (int kt=0; kt<nk; ++kt){
    const int buf = kt & 3;                          // nk divisible by 4 here (64, 64)
    if (kt+3 < nk) stage(kt+3, (kt+3) & 3);
    const u16* Ab = &L[buf*16384];
    const u16* Bb = Ab + 8192;
    bf16x8 a[8], b[4];
#pragma unroll
    for (int mi=0;mi<8;mi++){
      const int row = wm*128 + mi*16 + lr;
      a[mi] = *(const bf16x8*)&Ab[row*32 + ((lg ^ ((row ^ (row>>2))&3))*8)];
    }
#pragma unroll
    for (int ni=0;ni<4;ni++){
      const int row = wn*64 + ni*16 + lr;
      b[ni] = *(const bf16x8*)&Bb[row*32 + ((lg ^ ((row ^ (row>>2))&3))*8)];
    }
#pragma unroll
    for (int mi=0;mi<8;mi++)
#pragma unroll
      for (int ni=0;ni<4;ni++)
        acc[mi][ni] = __builtin_amdgcn_mfma_f32_16x16x32_bf16(a[mi], b[ni], acc[mi][ni], 0,0,0);
    __builtin_amdgcn_sched_barrier(0);               // pin reads/stage above the wait
    if      (kt+3 < nk) asm volatile("s_waitcnt vmcnt(8)" ::: "memory");
    else if (kt+2 < nk) asm volatile("s_waitcnt vmcnt(4)" ::: "memory");
    else                asm volatile("s_waitcnt vmcnt(0)" ::: "memory");
    __builtin_amdgcn_s_barrier();                    // raw barrier: no compiler drain
    __builtin_amdgcn_sched_barrier(0);
  }

  // ---- epilogue with fused RoPE (+ q pre-scale) ----
  const float S2q = 0.08838834764831845f * 1.4426950408889634f;
#pragma unroll
  for (int mi=0;mi<8;mi++)
#pragma unroll
    for (int ni=0;ni<4;ni++){
      const int col = tn + wn*64 + ni*16 + lr;
      const bool doRope = col < 3072;                // q,k cols (wave-uniform per ni)
      const float S2 = (col < 2048) ? S2q : 1.0f;
      const int fi = (col >> 1) & 63;                // freq index (pair within head)
      const bool odd = (lr & 1) != 0;
#pragma unroll
      for (int reg=0;reg<4;reg++){
        const int row = tm + wm*128 + mi*16 + lg*4 + reg;
        float x = acc[mi][ni][reg];
        const float xp = __shfl_xor(x, 1);           // partner element of the pair
        if (doRope){
          const int t = row & 2047;
          const float c = fc[t*64 + fi];
          const float s = fs[t*64 + fi];
          x = odd ? (xp*s + x*c) : (x*c - xp*s);
          x *= S2;
        }
        Cv[(size_t)row*N + col] = f2b(x);
      }
    }
}

// ---------------- causal GQA flash attention v7 (R12-exact, ~109us) ----------------
__global__ __launch_bounds__(512, 1) void attn_k(const u16* __restrict__ qkv,
                                                 const u16* __restrict__ vT,
                                                 u16* __restrict__ y){
  __shared__ __align__(16) u16 KV[2][2][16384];
  const int i0 = blockIdx.x;
  const int g  = i0 & 7;
  const int r1 = i0 >> 3;
  const int hl = r1 & 1;
  const int vq = (r1 >> 1) & 7;
  const int b  = r1 >> 4;
  const int h  = g*2 + hl;

  const int tid = threadIdx.x;
  const int w = tid >> 6, l = tid & 63;
  const int grp = w >> 2, wq = w & 3;
  const int lq = l & 31;
  const int hi = l >> 5;

  const u16* kg = qkv + (size_t)(b*2048)*4096 + 2048 + g*128;
  const u16* vg = vT  + (size_t)(b*8+g)*128*2048;

  const int rk = tid >> 2, cb = tid & 3;
  uint4 kpre[4], vpre[4];
  auto loadT = [&](int kvbase){
#pragma unroll
    for (int j=0;j<4;j++){
      const int ch = cb + j*4;
      kpre[j] = *(const uint4*)(kg + (size_t)(kvbase + rk)*4096 + ch*8);
      vpre[j] = *(const uint4*)(vg + (size_t)rk*2048 + kvbase + ch*8);
    }
  };
  auto writeT = [&](int buf){
    u16* Kd = &KV[buf][rk>>6][0];
    const int rl = rk & 63;
#pragma unroll
    for (int j=0;j<4;j++){
      const int ch = cb + j*4;
      *(uint4*)&Kd[rl*128 + ((ch ^ (rl&15))*8)] = kpre[j];
    }
#pragma unroll
    for (int j=0;j<4;j++){
      const int ch = cb + j*4;
      u16* Vd = &KV[buf][ch>>3][8192];
      *(uint4*)&Vd[rk*64 + (((ch&7) ^ (rk&7))*8)] = vpre[j];
    }
  };

  int qt = vq;
  const int nA = vq + 1;
  bf16x8 qf[8];
  f32x16 yacc[4];
  float mrow, lsum;

  auto loadQ = [&]{
    const size_t qrow = (size_t)(b*2048 + qt*128 + wq*32 + lq);
    const u16* qp = qkv + qrow*4096 + h*128 + hi*8;
#pragma unroll
    for (int ds=0; ds<8; ++ds) qf[ds] = *(const bf16x8*)(qp + ds*16);
  };
  auto resetAcc = [&]{
#pragma unroll
    for (int dt=0; dt<4; ++dt)
#pragma unroll
      for (int r=0; r<16; ++r) yacc[dt][r] = 0.f;
    mrow = -1e30f; lsum = 0.f;
  };

  auto mergePhase = [&](u16* Mb){
    float* Mm = (float*)Mb; float* Ml = Mm + 128;
    u16* MOs = Mb + 512 + wq*4096;
    __syncthreads();
    if (grp == 1){
      if (l < 32){ Mm[wq*32 + l] = mrow; Ml[wq*32 + l] = lsum; }
#pragma unroll
      for (int dt=0; dt<4; ++dt)
#pragma unroll
        for (int rq=0; rq<4; ++rq){
          const int d0 = dt*32 + rq*8 + hi*4;
          uint32_t lo = pk2(yacc[dt][rq*4+0], yacc[dt][rq*4+1]);
          uint32_t hi2= pk2(yacc[dt][rq*4+2], yacc[dt][rq*4+3]);
          const int idx = (lq*128 + d0) ^ ((lq&7)<<3);
          *(uint2*)&MOs[idx] = make_uint2(lo, hi2);
        }
    }
    __syncthreads();
    if (grp == 0){
      const float mo = Mm[wq*32 + lq], lo_ = Ml[wq*32 + lq];
      const float ms = fmaxf(mrow, mo);
      const float ce = ex2(mrow - ms), co = ex2(mo - ms);
      const float inv = 1.f / (lsum*ce + lo_*co);
#pragma unroll
      for (int dt=0; dt<4; ++dt)
#pragma unroll
        for (int rq=0; rq<4; ++rq){
          const int d0 = dt*32 + rq*8 + hi*4;
          const int idx = (lq*128 + d0) ^ ((lq&7)<<3);
          uint2 pr = *(const uint2*)&MOs[idx];
          const float yo0 = b2f((u16)(pr.x & 0xffff)), yo1 = b2f((u16)(pr.x >> 16));
          const float yo2 = b2f((u16)(pr.y & 0xffff)), yo3 = b2f((u16)(pr.y >> 16));
          uint32_t lo = pk2((yacc[dt][rq*4+0]*ce + yo0*co)*inv, (yacc[dt][rq*4+1]*ce + yo1*co)*inv);
          uint32_t hi2= pk2((yacc[dt][rq*4+2]*ce + yo2*co)*inv, (yacc[dt][rq*4+3]*ce + yo3*co)*inv);
          *(uint2*)&MOs[idx] = make_uint2(lo, hi2);
        }
    }
    __syncthreads();
    const int qb2 = b*2048 + qt*128 + wq*32;
#pragma unroll
    for (int p=0; p<2; ++p){
      const int row = grp*16 + p*8 + (l>>3);
      const int gc = l & 7;
      const int idx0 = (row*128 + gc*16) ^ ((row&7)<<3);
      const int idx1 = (row*128 + gc*16 + 8) ^ ((row&7)<<3);
      uint4 v0 = *(const uint4*)&MOs[idx0];
      uint4 v1 = *(const uint4*)&MOs[idx1];
      u16* yp = y + (size_t)(qb2 + row)*2048 + h*128 + gc*16;
      *(uint4*)yp = v0;
      *(uint4*)(yp + 8) = v1;
    }
    __syncthreads();
  };

  loadT(0); writeT(0); __syncthreads();
  loadQ(); resetAcc();

  for (int s=0; s<17; ++s){
    if (s == nA){
      mergePhase(&KV[(nA&1)^1][0][0]);
      qt = 15 - vq;
      loadQ(); resetAcc();
    }
    const int sj = (s < nA) ? s : s - nA;
    const int kvbase = sj*128;
    if (s+1 < 17){
      const int s2 = s+1;
      const int sj2 = (s2 < nA) ? s2 : s2 - nA;
      loadT(sj2*128);
    }
    const u16* Kb = &KV[s&1][grp][0];
    const u16* Vb = Kb + 8192;
    const int tilebase = kvbase + grp*64;
    const int qmin = qt*128 + wq*32;
    const int qrow = qmin + lq;

    if (tilebase <= qmin + 31){
      f32x16 sc[2];
#pragma unroll
      for (int t=0;t<2;t++)
#pragma unroll
        for (int r=0;r<16;r++) sc[t][r] = 0.f;
      __builtin_amdgcn_s_setprio(1);
#pragma unroll
      for (int t=0; t<2; ++t){
        const int r = t*32 + lq;
        const int rsw = r & 15;
#pragma unroll
        for (int ds=0; ds<8; ++ds){
          const bf16x8 kf = *(const bf16x8*)&Kb[r*128 + (((2*ds+hi) ^ rsw)*8)];
          sc[t] = __builtin_amdgcn_mfma_f32_32x32x16_bf16(kf, qf[ds], sc[t], 0,0,0);
        }
      }
      __builtin_amdgcn_s_setprio(0);

      if (tilebase + 63 > qmin){
#pragma unroll
        for (int t=0;t<2;t++)
#pragma unroll
          for (int r=0;r<16;r++){
            const int kp = tilebase + t*32 + (r&3) + 8*(r>>2) + 4*hi;
            if (kp > qrow) sc[t][r] = -1e30f;
          }
      }

      float mx[16];
#pragma unroll
      for (int r=0;r<16;r++) mx[r] = fmaxf(sc[0][r], sc[1][r]);
#pragma unroll
      for (int off=8; off>0; off>>=1)
#pragma unroll
        for (int r=0;r<8;r++)
          if (r < off) mx[r] = fmaxf(mx[r], mx[r+off]);
      float pmax = fmaxf(mx[0], __shfl_xor(mx[0], 32));

      if (!__all(pmax <= mrow + 8.f)){
        const float mnew = fmaxf(mrow, pmax);
        const float corr = ex2(mrow - mnew);
        mrow = mnew; lsum *= corr;
#pragma unroll
        for (int dt=0;dt<4;dt++)
#pragma unroll
          for (int r=0;r<16;r++) yacc[dt][r] *= corr;
      }

#pragma unroll
      for (int t=0;t<2;t++)
#pragma unroll
        for (int r=0;r<16;r++) sc[t][r] = ex2(sc[t][r] - mrow);
      float sm[16];
#pragma unroll
      for (int r=0;r<16;r++) sm[r] = sc[0][r] + sc[1][r];
#pragma unroll
      for (int off=8; off>0; off>>=1)
#pragma unroll
        for (int r=0;r<8;r++)
          if (r < off) sm[r] += sm[r+off];
      lsum += sm[0] + __shfl_xor(sm[0], 32);

      __align__(16) uint32_t pw[4][4];
#pragma unroll
      for (int t=0;t<2;t++)
#pragma unroll
        for (int half=0; half<2; ++half){
          const int q8 = half*8;
          const uint32_t X0 = pk2(sc[t][q8+0], sc[t][q8+1]);
          const uint32_t X1 = pk2(sc[t][q8+2], sc[t][q8+3]);
          const uint32_t X2 = pk2(sc[t][q8+4], sc[t][q8+5]);
          const uint32_t X3 = pk2(sc[t][q8+6], sc[t][q8+7]);
          const uint32_t pX0 = (uint32_t)__shfl_xor((int)X0, 32);
          const uint32_t pX1 = (uint32_t)__shfl_xor((int)X1, 32);
          const uint32_t pX2 = (uint32_t)__shfl_xor((int)X2, 32);
          const uint32_t pX3 = (uint32_t)__shfl_xor((int)X3, 32);
          const int ks = t*2 + half;
          pw[ks][0] = hi ? pX2 : X0;
          pw[ks][1] = hi ? pX3 : X1;
          pw[ks][2] = hi ? X2 : pX0;
          pw[ks][3] = hi ? X3 : pX1;
        }

      __builtin_amdgcn_s_setprio(1);
#pragma unroll
      for (int dt=0; dt<4; ++dt){
        const int d = dt*32 + lq;
        const int dsw = d & 7;
#pragma unroll
        for (int ks=0; ks<4; ++ks){
          const bf16x8 vf = *(const bf16x8*)&Vb[d*64 + (((2*ks+hi) ^ dsw)*8)];
          yacc[dt] = __builtin_amdgcn_mfma_f32_32x32x16_bf16(vf, *(const bf16x8*)&pw[ks][0], yacc[dt], 0,0,0);
        }
      }
      __builtin_amdgcn_s_setprio(0);
    }

    if (s+1 < 17) writeT((s&1)^1);
    __syncthreads();
  }
  mergePhase(&KV[0][0][0]);
}

// ---------------- host ----------------
extern "C" void kernel_launch(void* const* d_in, const int* in_sizes, int n_in,
                              void* d_out, int out_size, void* d_ws, size_t ws_size,
                              hipStream_t stream){
  char* ws = (char*)d_ws;
  const size_t MB = 1048576;
  uint32_t* flag = (uint32_t*)(ws);
  float* fcF = (float*)(ws + 1*MB);
  float* fsF = (float*)(ws + 1*MB + 524288);
  u16* xb   = (u16*)(ws + 2*MB);           // 16 MB (reused as yb after gemm1)
  u16* waT  = (u16*)(ws + 18*MB);          // 16 MB
  u16* wpT  = (u16*)(ws + 34*MB);          // 8 MB
  u16* qkvb = (u16*)(ws + 42*MB);          // 32 MB
  u16* vTb  = (u16*)(ws + 74*MB);          // 8 MB
  u16* yb   = xb;

  detect_k<<<1, 64, 0, stream>>>((const uint32_t*)d_in[3], flag);
  cvtf2_k <<<1024, 256, 0, stream>>>(d_in[3], d_in[4], fcF, fsF, 131072, flag);
  cvtx_k  <<<4096, 256, 0, stream>>>(d_in[0], xb, 1048576, flag);
  wtrans_k<<<dim3(64,32,1), 512, 0, stream>>>(d_in[1], waT, 4096, 2048, flag);
  wtrans_k<<<dim3(32,32,1), 512, 0, stream>>>(d_in[2], wpT, 2048, 2048, flag);
  gemm_q  <<<dim3(256,1,1), 512, 0, stream>>>(xb, waT, qkvb, 4096, 4096, 2048, fcF, fsF);
  vtrans_k<<<dim3(2,32,16), 512, 0, stream>>>(qkvb, vTb);
  attn_k  <<<dim3(256,1,1), 512, 0, stream>>>(qkvb, vTb, yb);
  gemm_p  <<<dim3(256,1,1), 512, 0, stream>>>(yb, wpT, d_out, 4096, 2048, 2048, flag, 1);
}

// Round 18
// 257.181 us; speedup vs baseline: 1.0315x; 1.0315x over previous
//
#include <hip/hip_runtime.h>
#include <hip/hip_bf16.h>
#include <stdint.h>
#include <stddef.h>

typedef unsigned short u16;
using bf16x8 = __attribute__((ext_vector_type(8))) short;   // 8 bf16 = 4 VGPR
using f32x4  = __attribute__((ext_vector_type(4))) float;
using f32x16 = __attribute__((ext_vector_type(16))) float;

#define DEVFN static __device__ __forceinline__

DEVFN u16 f2b(float f){ __hip_bfloat16 h = __float2bfloat16(f); return *reinterpret_cast<u16*>(&h); }
DEVFN float b2f(u16 u){ __hip_bfloat16 h; *reinterpret_cast<u16*>(&h) = u; return __bfloat162float(h); }
DEVFN uint32_t pk2(float a, float b){
  uint32_t r; asm("v_cvt_pk_bf16_f32 %0, %1, %2" : "=v"(r) : "v"(a), "v"(b)); return r;
}
DEVFN float ex2(float x){ float r; asm("v_exp_f32 %0, %1" : "=v"(r) : "v"(x)); return r; }

DEVFN void gload_lds16(const void* g, void* l){
  __builtin_amdgcn_global_load_lds(
      (const __attribute__((address_space(1))) void*)g,
      (__attribute__((address_space(3))) void*)l, 16, 0, 0);
}

// ---------------- dtype detect: freqs_cos[0]==1.0f -> f32 (0x3F800000), bf16 pair -> 0x3F803F80
__global__ void detect_k(const uint32_t* __restrict__ fc_raw, uint32_t* __restrict__ flag){
  if (threadIdx.x == 0 && blockIdx.x == 0)
    flag[0] = (fc_raw[0] == 0x3F800000u) ? 1u : 0u;
}

// ---------------- both freq tables -> f32, one launch ----------------
__global__ __launch_bounds__(256) void cvtf2_k(const void* __restrict__ inc, const void* __restrict__ ins,
                                               float* __restrict__ outc, float* __restrict__ outs,
                                               int n, const uint32_t* __restrict__ flag){
  const int i = blockIdx.x*256 + threadIdx.x;
  const bool f32in = flag[0] != 0;
  if (i < n){
    outc[i] = f32in ? ((const float*)inc)[i] : b2f(((const u16*)inc)[i]);
  } else if (i < 2*n){
    const int k = i - n;
    outs[k] = f32in ? ((const float*)ins)[k] : b2f(((const u16*)ins)[k]);
  }
}

// ---------------- x -> bf16 (8 elems/thread) ----------------
__global__ __launch_bounds__(256) void cvtx_k(const void* __restrict__ in, u16* __restrict__ out,
                                              int n8, const uint32_t* __restrict__ flag){
  const int i = blockIdx.x*256 + threadIdx.x;
  if (i >= n8) return;
  __align__(16) u16 e[8];
  if (flag[0]){
    const float* f = (const float*)in + (size_t)i*8;
    float4 a = *(const float4*)f, b = *(const float4*)(f+4);
    e[0]=f2b(a.x); e[1]=f2b(a.y); e[2]=f2b(a.z); e[3]=f2b(a.w);
    e[4]=f2b(b.x); e[5]=f2b(b.y); e[6]=f2b(b.z); e[7]=f2b(b.w);
  } else {
    *(uint4*)e = *((const uint4*)in + i);
  }
  *(uint4*)(out + (size_t)i*8) = *(const uint4*)e;
}

// ---------------- weight transpose (+dtype cvt): in (R x C) -> out bf16 (C x R) ----------------
__global__ __launch_bounds__(512) void wtrans_k(const void* __restrict__ in, u16* __restrict__ out,
                                                int C, int R, const uint32_t* __restrict__ flag){
  __shared__ __align__(16) u16 tile[64][72];
  const int r0 = blockIdx.y*64, c0 = blockIdx.x*64;
  const int t = threadIdx.x, r = t>>3, cs = (t&7)*8;
  __align__(16) u16 e[8];
  if (flag[0]){
    const float* f = (const float*)in + (size_t)(r0+r)*C + c0 + cs;
    float4 a = *(const float4*)f, b = *(const float4*)(f+4);
    e[0]=f2b(a.x); e[1]=f2b(a.y); e[2]=f2b(a.z); e[3]=f2b(a.w);
    e[4]=f2b(b.x); e[5]=f2b(b.y); e[6]=f2b(b.z); e[7]=f2b(b.w);
  } else {
    *(uint4*)e = *(const uint4*)((const u16*)in + (size_t)(r0+r)*C + c0 + cs);
  }
#pragma unroll
  for (int j=0;j<8;j++) tile[cs+j][r] = e[j];
  __syncthreads();
  uint4 o = *(const uint4*)&tile[r][cs];
  *(uint4*)(out + (size_t)(c0+r)*R + r0 + cs) = o;
}

// ---------------- V transpose: qkv v-slice (t x d) -> vT[(b*8+g)*128 + d][t] ----------------
__global__ __launch_bounds__(512) void vtrans_k(const u16* __restrict__ qkv, u16* __restrict__ vT){
  __shared__ __align__(16) u16 tile[64][72];
  const int z = blockIdx.z, b = z>>3, g = z&7;
  const u16* in = qkv + (size_t)(b*2048)*4096 + 3072 + g*128;
  u16* out = vT + (size_t)z*128*2048;
  const int r0 = blockIdx.y*64, c0 = blockIdx.x*64;   // r0 over t, c0 over d
  const int t = threadIdx.x, r = t>>3, cs = (t&7)*8;
  uint4 v = *(const uint4*)(in + (size_t)(r0+r)*4096 + c0 + cs);
  const u16* e = (const u16*)&v;
#pragma unroll
  for (int j=0;j<8;j++) tile[cs+j][r] = e[j];
  __syncthreads();
  uint4 o = *(const uint4*)&tile[r][cs];
  *(uint4*)(out + (size_t)(c0+r)*2048 + r0 + cs) = o;
}

// ---------------- RoPE, 8 pairs/thread; q rows pre-scaled by 1/sqrt(D)*log2(e) ----------------
__global__ __launch_bounds__(192) void rope8_k(u16* qkv, const float* __restrict__ fc,
                                               const float* __restrict__ fs){
  const int row = blockIdx.x;
  const int j = threadIdx.x;
  const int p0 = j*8;
  const int t = row & 2047;
  const int i0 = p0 & 63;
  uint4* ptr = (uint4*)(qkv + (size_t)row*4096 + p0*2);
  uint4 u0 = ptr[0], u1 = ptr[1];
  const float* fcp = fc + t*64 + i0;
  const float* fsp = fs + t*64 + i0;
  float4 c0 = *(const float4*)fcp, c1 = *(const float4*)(fcp+4);
  float4 s0 = *(const float4*)fsp, s1 = *(const float4*)(fsp+4);
  const float S2 = (p0 < 1024) ? (0.08838834764831845f * 1.4426950408889634f) : 1.0f;
  uint32_t wd[8] = {u0.x,u0.y,u0.z,u0.w,u1.x,u1.y,u1.z,u1.w};
  const float cc[8] = {c0.x,c0.y,c0.z,c0.w,c1.x,c1.y,c1.z,c1.w};
  const float ss[8] = {s0.x,s0.y,s0.z,s0.w,s1.x,s1.y,s1.z,s1.w};
#pragma unroll
  for (int k=0;k<8;k++){
    const float x0 = b2f((u16)(wd[k] & 0xffff));
    const float x1 = b2f((u16)(wd[k] >> 16));
    const float o0 = (x0*cc[k] - x1*ss[k]) * S2;
    const float o1 = (x0*ss[k] + x1*cc[k]) * S2;
    wd[k] = pk2(o0, o1);
  }
  u0 = make_uint4(wd[0],wd[1],wd[2],wd[3]);
  u1 = make_uint4(wd[4],wd[5],wd[6],wd[7]);
  ptr[0] = u0; ptr[1] = u1;
}

// ---------------- pipelined GEMM v1: BM=256, BN=128 (proj) ----------------
__global__ __launch_bounds__(512) void gemm_p(const u16* __restrict__ A, const u16* __restrict__ Bt,
                                              void* __restrict__ Cv, int M, int N, int K,
                                              const uint32_t* __restrict__ flag, int fin){
  __shared__ __align__(16) u16 L[3*12288];
  const int nwg_x = N>>7;
  int wg = blockIdx.x;
  { const int cpx = (int)gridDim.x >> 3; wg = (wg&7)*cpx + (wg>>3); }
  const int tm = (wg / nwg_x)*256, tn = (wg % nwg_x)*128;
  const int tid = threadIdx.x, w = tid>>6, l = tid&63, lr = l&15, lg = l>>4;
  const int wm = w>>1, wn = w&1;

  f32x4 acc[4][4] = {};

  auto stage = [&](int kt, int buf){
    const int kk = kt*32;
    u16* Lb = &L[buf*12288];
#pragma unroll
    for (int j=0;j<2;j++){
      const int s = j*512 + tid;
      const int row = s>>2, c = s&3;
      const int gch = c ^ ((row ^ (row>>2)) & 3);
      gload_lds16(A + (size_t)(tm + row)*K + kk + gch*8, &Lb[(j*512 + w*64)*8]);
    }
    {
      const int s = tid;
      const int row = s>>2, c = s&3;
      const int gch = c ^ ((row ^ (row>>2)) & 3);
      gload_lds16(Bt + (size_t)(tn + row)*K + kk + gch*8, &Lb[8192 + (w*64)*8]);
    }
  };

  const int nk = K>>5;
  stage(0,0); stage(1,1);
  asm volatile("s_waitcnt vmcnt(3)" ::: "memory");
  __builtin_amdgcn_s_barrier();
  __builtin_amdgcn_sched_barrier(0);

  for (int kt=0; kt<nk; ++kt){
    const int buf = kt % 3;
    if (kt+2 < nk) stage(kt+2, (kt+2) % 3);
    const u16* Ab = &L[buf*12288];
    const u16* Bb = Ab + 8192;
    bf16x8 a[4], b[4];
#pragma unroll
    for (int mi=0;mi<4;mi++){
      const int row = wm*64 + mi*16 + lr;
      a[mi] = *(const bf16x8*)&Ab[row*32 + ((lg ^ ((row ^ (row>>2))&3))*8)];
    }
#pragma unroll
    for (int ni=0;ni<4;ni++){
      const int row = wn*64 + ni*16 + lr;
      b[ni] = *(const bf16x8*)&Bb[row*32 + ((lg ^ ((row ^ (row>>2))&3))*8)];
    }
#pragma unroll
    for (int mi=0;mi<4;mi++)
#pragma unroll
      for (int ni=0;ni<4;ni++)
        acc[mi][ni] = __builtin_amdgcn_mfma_f32_16x16x32_bf16(a[mi], b[ni], acc[mi][ni], 0,0,0);
    __builtin_amdgcn_sched_barrier(0);
    if (kt+2 < nk) asm volatile("s_waitcnt vmcnt(3)" ::: "memory");
    else           asm volatile("s_waitcnt vmcnt(0)" ::: "memory");
    __builtin_amdgcn_s_barrier();
    __builtin_amdgcn_sched_barrier(0);
  }

  const bool of32 = fin && (flag[0] != 0);
#pragma unroll
  for (int mi=0;mi<4;mi++)
#pragma unroll
    for (int ni=0;ni<4;ni++)
#pragma unroll
      for (int reg=0;reg<4;reg++){
        const int row = tm + wm*64 + mi*16 + lg*4 + reg;
        const int col = tn + wn*64 + ni*16 + lr;
        const size_t idx = (size_t)row*N + col;
        const float v = acc[mi][ni][reg];
        if (of32) ((float*)Cv)[idx] = v;
        else      ((u16*)Cv)[idx]   = f2b(v);
      }
}

// ---------------- pipelined GEMM v2: BM=BN=256, per-wave 128x64 (qkv) ----------------
__global__ __launch_bounds__(512) void gemm_p2(const u16* __restrict__ A, const u16* __restrict__ Bt,
                                               void* __restrict__ Cv, int M, int N, int K,
                                               const uint32_t* __restrict__ flag, int fin){
  __shared__ __align__(16) u16 L[3*16384];
  const int nwg_x = N>>8;
  int wg = blockIdx.x;
  { const int cpx = (int)gridDim.x >> 3; wg = (wg&7)*cpx + (wg>>3); }
  const int tm = (wg / nwg_x)*256, tn = (wg % nwg_x)*256;
  const int tid = threadIdx.x, w = tid>>6, l = tid&63, lr = l&15, lg = l>>4;
  const int wm = w>>2, wn = w&3;

  f32x4 acc[8][4] = {};

  auto stage = [&](int kt, int buf){
    const int kk = kt*32;
    u16* Lb = &L[buf*16384];
#pragma unroll
    for (int j=0;j<2;j++){
      const int s = j*512 + tid;
      const int row = s>>2, c = s&3;
      const int gch = c ^ ((row ^ (row>>2)) & 3);
      gload_lds16(A + (size_t)(tm + row)*K + kk + gch*8, &Lb[(j*512 + w*64)*8]);
    }
#pragma unroll
    for (int j=0;j<2;j++){
      const int s = j*512 + tid;
      const int row = s>>2, c = s&3;
      const int gch = c ^ ((row ^ (row>>2)) & 3);
      gload_lds16(Bt + (size_t)(tn + row)*K + kk + gch*8, &Lb[8192 + (j*512 + w*64)*8]);
    }
  };

  const int nk = K>>5;
  stage(0,0); stage(1,1);
  asm volatile("s_waitcnt vmcnt(4)" ::: "memory");
  __builtin_amdgcn_s_barrier();
  __builtin_amdgcn_sched_barrier(0);

  for (int kt=0; kt<nk; ++kt){
    const int buf = kt % 3;
    if (kt+2 < nk) stage(kt+2, (kt+2) % 3);
    const u16* Ab = &L[buf*16384];
    const u16* Bb = Ab + 8192;
    bf16x8 a[8], b[4];
#pragma unroll
    for (int mi=0;mi<8;mi++){
      const int row = wm*128 + mi*16 + lr;
      a[mi] = *(const bf16x8*)&Ab[row*32 + ((lg ^ ((row ^ (row>>2))&3))*8)];
    }
#pragma unroll
    for (int ni=0;ni<4;ni++){
      const int row = wn*64 + ni*16 + lr;
      b[ni] = *(const bf16x8*)&Bb[row*32 + ((lg ^ ((row ^ (row>>2))&3))*8)];
    }
#pragma unroll
    for (int mi=0;mi<8;mi++)
#pragma unroll
      for (int ni=0;ni<4;ni++)
        acc[mi][ni] = __builtin_amdgcn_mfma_f32_16x16x32_bf16(a[mi], b[ni], acc[mi][ni], 0,0,0);
    __builtin_amdgcn_sched_barrier(0);
    if (kt+2 < nk) asm volatile("s_waitcnt vmcnt(4)" ::: "memory");
    else           asm volatile("s_waitcnt vmcnt(0)" ::: "memory");
    __builtin_amdgcn_s_barrier();
    __builtin_amdgcn_sched_barrier(0);
  }

  const bool of32 = fin && (flag[0] != 0);
#pragma unroll
  for (int mi=0;mi<8;mi++)
#pragma unroll
    for (int ni=0;ni<4;ni++)
#pragma unroll
      for (int reg=0;reg<4;reg++){
        const int row = tm + wm*128 + mi*16 + lg*4 + reg;
        const int col = tn + wn*64 + ni*16 + lr;
        const size_t idx = (size_t)row*N + col;
        const float v = acc[mi][ni][reg];
        if (of32) ((float*)Cv)[idx] = v;
        else      ((u16*)Cv)[idx]   = f2b(v);
      }
}

// ---------------- causal GQA flash attention v7 (R12-exact, ~109us) ----------------
__global__ __launch_bounds__(512, 1) void attn_k(const u16* __restrict__ qkv,
                                                 const u16* __restrict__ vT,
                                                 u16* __restrict__ y){
  __shared__ __align__(16) u16 KV[2][2][16384];
  const int i0 = blockIdx.x;
  const int g  = i0 & 7;
  const int r1 = i0 >> 3;
  const int hl = r1 & 1;
  const int vq = (r1 >> 1) & 7;
  const int b  = r1 >> 4;
  const int h  = g*2 + hl;

  const int tid = threadIdx.x;
  const int w = tid >> 6, l = tid & 63;
  const int grp = w >> 2, wq = w & 3;
  const int lq = l & 31;
  const int hi = l >> 5;

  const u16* kg = qkv + (size_t)(b*2048)*4096 + 2048 + g*128;
  const u16* vg = vT  + (size_t)(b*8+g)*128*2048;

  const int rk = tid >> 2, cb = tid & 3;
  uint4 kpre[4], vpre[4];
  auto loadT = [&](int kvbase){
#pragma unroll
    for (int j=0;j<4;j++){
      const int ch = cb + j*4;
      kpre[j] = *(const uint4*)(kg + (size_t)(kvbase + rk)*4096 + ch*8);
      vpre[j] = *(const uint4*)(vg + (size_t)rk*2048 + kvbase + ch*8);
    }
  };
  auto writeT = [&](int buf){
    u16* Kd = &KV[buf][rk>>6][0];
    const int rl = rk & 63;
#pragma unroll
    for (int j=0;j<4;j++){
      const int ch = cb + j*4;
      *(uint4*)&Kd[rl*128 + ((ch ^ (rl&15))*8)] = kpre[j];
    }
#pragma unroll
    for (int j=0;j<4;j++){
      const int ch = cb + j*4;
      u16* Vd = &KV[buf][ch>>3][8192];
      *(uint4*)&Vd[rk*64 + (((ch&7) ^ (rk&7))*8)] = vpre[j];
    }
  };

  int qt = vq;
  const int nA = vq + 1;
  bf16x8 qf[8];
  f32x16 yacc[4];
  float mrow, lsum;

  auto loadQ = [&]{
    const size_t qrow = (size_t)(b*2048 + qt*128 + wq*32 + lq);
    const u16* qp = qkv + qrow*4096 + h*128 + hi*8;
#pragma unroll
    for (int ds=0; ds<8; ++ds) qf[ds] = *(const bf16x8*)(qp + ds*16);
  };
  auto resetAcc = [&]{
#pragma unroll
    for (int dt=0; dt<4; ++dt)
#pragma unroll
      for (int r=0; r<16; ++r) yacc[dt][r] = 0.f;
    mrow = -1e30f; lsum = 0.f;
  };

  auto mergePhase = [&](u16* Mb){
    float* Mm = (float*)Mb; float* Ml = Mm + 128;
    u16* MOs = Mb + 512 + wq*4096;
    __syncthreads();
    if (grp == 1){
      if (l < 32){ Mm[wq*32 + l] = mrow; Ml[wq*32 + l] = lsum; }
#pragma unroll
      for (int dt=0; dt<4; ++dt)
#pragma unroll
        for (int rq=0; rq<4; ++rq){
          const int d0 = dt*32 + rq*8 + hi*4;
          uint32_t lo = pk2(yacc[dt][rq*4+0], yacc[dt][rq*4+1]);
          uint32_t hi2= pk2(yacc[dt][rq*4+2], yacc[dt][rq*4+3]);
          const int idx = (lq*128 + d0) ^ ((lq&7)<<3);
          *(uint2*)&MOs[idx] = make_uint2(lo, hi2);
        }
    }
    __syncthreads();
    if (grp == 0){
      const float mo = Mm[wq*32 + lq], lo_ = Ml[wq*32 + lq];
      const float ms = fmaxf(mrow, mo);
      const float ce = ex2(mrow - ms), co = ex2(mo - ms);
      const float inv = 1.f / (lsum*ce + lo_*co);
#pragma unroll
      for (int dt=0; dt<4; ++dt)
#pragma unroll
        for (int rq=0; rq<4; ++rq){
          const int d0 = dt*32 + rq*8 + hi*4;
          const int idx = (lq*128 + d0) ^ ((lq&7)<<3);
          uint2 pr = *(const uint2*)&MOs[idx];
          const float yo0 = b2f((u16)(pr.x & 0xffff)), yo1 = b2f((u16)(pr.x >> 16));
          const float yo2 = b2f((u16)(pr.y & 0xffff)), yo3 = b2f((u16)(pr.y >> 16));
          uint32_t lo = pk2((yacc[dt][rq*4+0]*ce + yo0*co)*inv, (yacc[dt][rq*4+1]*ce + yo1*co)*inv);
          uint32_t hi2= pk2((yacc[dt][rq*4+2]*ce + yo2*co)*inv, (yacc[dt][rq*4+3]*ce + yo3*co)*inv);
          *(uint2*)&MOs[idx] = make_uint2(lo, hi2);
        }
    }
    __syncthreads();
    const int qb2 = b*2048 + qt*128 + wq*32;
#pragma unroll
    for (int p=0; p<2; ++p){
      const int row = grp*16 + p*8 + (l>>3);
      const int gc = l & 7;
      const int idx0 = (row*128 + gc*16) ^ ((row&7)<<3);
      const int idx1 = (row*128 + gc*16 + 8) ^ ((row&7)<<3);
      uint4 v0 = *(const uint4*)&MOs[idx0];
      uint4 v1 = *(const uint4*)&MOs[idx1];
      u16* yp = y + (size_t)(qb2 + row)*2048 + h*128 + gc*16;
      *(uint4*)yp = v0;
      *(uint4*)(yp + 8) = v1;
    }
    __syncthreads();
  };

  loadT(0); writeT(0); __syncthreads();
  loadQ(); resetAcc();

  for (int s=0; s<17; ++s){
    if (s == nA){
      mergePhase(&KV[(nA&1)^1][0][0]);
      qt = 15 - vq;
      loadQ(); resetAcc();
    }
    const int sj = (s < nA) ? s : s - nA;
    const int kvbase = sj*128;
    if (s+1 < 17){
      const int s2 = s+1;
      const int sj2 = (s2 < nA) ? s2 : s2 - nA;
      loadT(sj2*128);
    }
    const u16* Kb = &KV[s&1][grp][0];
    const u16* Vb = Kb + 8192;
    const int tilebase = kvbase + grp*64;
    const int qmin = qt*128 + wq*32;
    const int qrow = qmin + lq;

    if (tilebase <= qmin + 31){
      f32x16 sc[2];
#pragma unroll
      for (int t=0;t<2;t++)
#pragma unroll
        for (int r=0;r<16;r++) sc[t][r] = 0.f;
      __builtin_amdgcn_s_setprio(1);
#pragma unroll
      for (int t=0; t<2; ++t){
        const int r = t*32 + lq;
        const int rsw = r & 15;
#pragma unroll
        for (int ds=0; ds<8; ++ds){
          const bf16x8 kf = *(const bf16x8*)&Kb[r*128 + (((2*ds+hi) ^ rsw)*8)];
          sc[t] = __builtin_amdgcn_mfma_f32_32x32x16_bf16(kf, qf[ds], sc[t], 0,0,0);
        }
      }
      __builtin_amdgcn_s_setprio(0);

      if (tilebase + 63 > qmin){
#pragma unroll
        for (int t=0;t<2;t++)
#pragma unroll
          for (int r=0;r<16;r++){
            const int kp = tilebase + t*32 + (r&3) + 8*(r>>2) + 4*hi;
            if (kp > qrow) sc[t][r] = -1e30f;
          }
      }

      float mx[16];
#pragma unroll
      for (int r=0;r<16;r++) mx[r] = fmaxf(sc[0][r], sc[1][r]);
#pragma unroll
      for (int off=8; off>0; off>>=1)
#pragma unroll
        for (int r=0;r<8;r++)
          if (r < off) mx[r] = fmaxf(mx[r], mx[r+off]);
      float pmax = fmaxf(mx[0], __shfl_xor(mx[0], 32));

      if (!__all(pmax <= mrow + 8.f)){
        const float mnew = fmaxf(mrow, pmax);
        const float corr = ex2(mrow - mnew);
        mrow = mnew; lsum *= corr;
#pragma unroll
        for (int dt=0;dt<4;dt++)
#pragma unroll
          for (int r=0;r<16;r++) yacc[dt][r] *= corr;
      }

#pragma unroll
      for (int t=0;t<2;t++)
#pragma unroll
        for (int r=0;r<16;r++) sc[t][r] = ex2(sc[t][r] - mrow);
      float sm[16];
#pragma unroll
      for (int r=0;r<16;r++) sm[r] = sc[0][r] + sc[1][r];
#pragma unroll
      for (int off=8; off>0; off>>=1)
#pragma unroll
        for (int r=0;r<8;r++)
          if (r < off) sm[r] += sm[r+off];
      lsum += sm[0] + __shfl_xor(sm[0], 32);

      __align__(16) uint32_t pw[4][4];
#pragma unroll
      for (int t=0;t<2;t++)
#pragma unroll
        for (int half=0; half<2; ++half){
          const int q8 = half*8;
          const uint32_t X0 = pk2(sc[t][q8+0], sc[t][q8+1]);
          const uint32_t X1 = pk2(sc[t][q8+2], sc[t][q8+3]);
          const uint32_t X2 = pk2(sc[t][q8+4], sc[t][q8+5]);
          const uint32_t X3 = pk2(sc[t][q8+6], sc[t][q8+7]);
          const uint32_t pX0 = (uint32_t)__shfl_xor((int)X0, 32);
          const uint32_t pX1 = (uint32_t)__shfl_xor((int)X1, 32);
          const uint32_t pX2 = (uint32_t)__shfl_xor((int)X2, 32);
          const uint32_t pX3 = (uint32_t)__shfl_xor((int)X3, 32);
          const int ks = t*2 + half;
          pw[ks][0] = hi ? pX2 : X0;
          pw[ks][1] = hi ? pX3 : X1;
          pw[ks][2] = hi ? X2 : pX0;
          pw[ks][3] = hi ? X3 : pX1;
        }

      __builtin_amdgcn_s_setprio(1);
#pragma unroll
      for (int dt=0; dt<4; ++dt){
        const int d = dt*32 + lq;
        const int dsw = d & 7;
#pragma unroll
        for (int ks=0; ks<4; ++ks){
          const bf16x8 vf = *(const bf16x8*)&Vb[d*64 + (((2*ks+hi) ^ dsw)*8)];
          yacc[dt] = __builtin_amdgcn_mfma_f32_32x32x16_bf16(vf, *(const bf16x8*)&pw[ks][0], yacc[dt], 0,0,0);
        }
      }
      __builtin_amdgcn_s_setprio(0);
    }

    if (s+1 < 17) writeT((s&1)^1);
    __syncthreads();
  }
  mergePhase(&KV[0][0][0]);
}

// ---------------- host ----------------
extern "C" void kernel_launch(void* const* d_in, const int* in_sizes, int n_in,
                              void* d_out, int out_size, void* d_ws, size_t ws_size,
                              hipStream_t stream){
  char* ws = (char*)d_ws;
  const size_t MB = 1048576;
  uint32_t* flag = (uint32_t*)(ws);
  float* fcF = (float*)(ws + 1*MB);
  float* fsF = (float*)(ws + 1*MB + 524288);
  u16* xb   = (u16*)(ws + 2*MB);           // 16 MB (reused as yb after gemm1)
  u16* waT  = (u16*)(ws + 18*MB);          // 16 MB
  u16* wpT  = (u16*)(ws + 34*MB);          // 8 MB
  u16* qkvb = (u16*)(ws + 42*MB);          // 32 MB
  u16* vTb  = (u16*)(ws + 74*MB);          // 8 MB
  u16* yb   = xb;

  detect_k<<<1, 64, 0, stream>>>((const uint32_t*)d_in[3], flag);
  cvtf2_k <<<1024, 256, 0, stream>>>(d_in[3], d_in[4], fcF, fsF, 131072, flag);
  cvtx_k  <<<4096, 256, 0, stream>>>(d_in[0], xb, 1048576, flag);
  wtrans_k<<<dim3(64,32,1), 512, 0, stream>>>(d_in[1], waT, 4096, 2048, flag);
  wtrans_k<<<dim3(32,32,1), 512, 0, stream>>>(d_in[2], wpT, 2048, 2048, flag);
  gemm_p2 <<<dim3(256,1,1), 512, 0, stream>>>(xb, waT, qkvb, 4096, 4096, 2048, flag, 0);
  rope8_k <<<dim3(4096,1,1), 192, 0, stream>>>(qkvb, fcF, fsF);
  vtrans_k<<<dim3(2,32,16), 512, 0, stream>>>(qkvb, vTb);
  attn_k  <<<dim3(256,1,1), 512, 0, stream>>>(qkvb, vTb, yb);
  gemm_p  <<<dim3(256,1,1), 512, 0, stream>>>(yb, wpT, d_out, 4096, 2048, 2048, flag, 1);
}

// Round 19
// 256.498 us; speedup vs baseline: 1.0343x; 1.0027x over previous
//
#include <hip/hip_runtime.h>
#include <hip/hip_bf16.h>
#include <stdint.h>
#include <stddef.h>

typedef unsigned short u16;
using bf16x8 = __attribute__((ext_vector_type(8))) short;   // 8 bf16 = 4 VGPR
using f32x4  = __attribute__((ext_vector_type(4))) float;
using f32x16 = __attribute__((ext_vector_type(16))) float;

#define DEVFN static __device__ __forceinline__

DEVFN u16 f2b(float f){ __hip_bfloat16 h = __float2bfloat16(f); return *reinterpret_cast<u16*>(&h); }
DEVFN float b2f(u16 u){ __hip_bfloat16 h; *reinterpret_cast<u16*>(&h) = u; return __bfloat162float(h); }
DEVFN uint32_t pk2(float a, float b){
  uint32_t r; asm("v_cvt_pk_bf16_f32 %0, %1, %2" : "=v"(r) : "v"(a), "v"(b)); return r;
}
DEVFN float ex2(float x){ float r; asm("v_exp_f32 %0, %1" : "=v"(r) : "v"(x)); return r; }

DEVFN void gload_lds16(const void* g, void* l){
  __builtin_amdgcn_global_load_lds(
      (const __attribute__((address_space(1))) void*)g,
      (__attribute__((address_space(3))) void*)l, 16, 0, 0);
}

// ---------------- dtype detect: freqs_cos[0]==1.0f -> f32 (0x3F800000), bf16 pair -> 0x3F803F80
__global__ void detect_k(const uint32_t* __restrict__ fc_raw, uint32_t* __restrict__ flag){
  if (threadIdx.x == 0 && blockIdx.x == 0)
    flag[0] = (fc_raw[0] == 0x3F800000u) ? 1u : 0u;
}

// ---------------- both freq tables -> f32, one launch ----------------
__global__ __launch_bounds__(256) void cvtf2_k(const void* __restrict__ inc, const void* __restrict__ ins,
                                               float* __restrict__ outc, float* __restrict__ outs,
                                               int n, const uint32_t* __restrict__ flag){
  const int i = blockIdx.x*256 + threadIdx.x;
  const bool f32in = flag[0] != 0;
  if (i < n){
    outc[i] = f32in ? ((const float*)inc)[i] : b2f(((const u16*)inc)[i]);
  } else if (i < 2*n){
    const int k = i - n;
    outs[k] = f32in ? ((const float*)ins)[k] : b2f(((const u16*)ins)[k]);
  }
}

// ---------------- x -> bf16 (8 elems/thread) ----------------
__global__ __launch_bounds__(256) void cvtx_k(const void* __restrict__ in, u16* __restrict__ out,
                                              int n8, const uint32_t* __restrict__ flag){
  const int i = blockIdx.x*256 + threadIdx.x;
  if (i >= n8) return;
  __align__(16) u16 e[8];
  if (flag[0]){
    const float* f = (const float*)in + (size_t)i*8;
    float4 a = *(const float4*)f, b = *(const float4*)(f+4);
    e[0]=f2b(a.x); e[1]=f2b(a.y); e[2]=f2b(a.z); e[3]=f2b(a.w);
    e[4]=f2b(b.x); e[5]=f2b(b.y); e[6]=f2b(b.z); e[7]=f2b(b.w);
  } else {
    *(uint4*)e = *((const uint4*)in + i);
  }
  *(uint4*)(out + (size_t)i*8) = *(const uint4*)e;
}

// ---------------- weight transpose (+dtype cvt): in (R x C) -> out bf16 (C x R) ----------------
__global__ __launch_bounds__(512) void wtrans_k(const void* __restrict__ in, u16* __restrict__ out,
                                                int C, int R, const uint32_t* __restrict__ flag){
  __shared__ __align__(16) u16 tile[64][72];
  const int r0 = blockIdx.y*64, c0 = blockIdx.x*64;
  const int t = threadIdx.x, r = t>>3, cs = (t&7)*8;
  __align__(16) u16 e[8];
  if (flag[0]){
    const float* f = (const float*)in + (size_t)(r0+r)*C + c0 + cs;
    float4 a = *(const float4*)f, b = *(const float4*)(f+4);
    e[0]=f2b(a.x); e[1]=f2b(a.y); e[2]=f2b(a.z); e[3]=f2b(a.w);
    e[4]=f2b(b.x); e[5]=f2b(b.y); e[6]=f2b(b.z); e[7]=f2b(b.w);
  } else {
    *(uint4*)e = *(const uint4*)((const u16*)in + (size_t)(r0+r)*C + c0 + cs);
  }
#pragma unroll
  for (int j=0;j<8;j++) tile[cs+j][r] = e[j];
  __syncthreads();
  uint4 o = *(const uint4*)&tile[r][cs];
  *(uint4*)(out + (size_t)(c0+r)*R + r0 + cs) = o;
}

// ---------------- V transpose: qkv v-slice (t x d) -> vT[(b*8+g)*128 + d][t] ----------------
__global__ __launch_bounds__(512) void vtrans_k(const u16* __restrict__ qkv, u16* __restrict__ vT){
  __shared__ __align__(16) u16 tile[64][72];
  const int z = blockIdx.z, b = z>>3, g = z&7;
  const u16* in = qkv + (size_t)(b*2048)*4096 + 3072 + g*128;
  u16* out = vT + (size_t)z*128*2048;
  const int r0 = blockIdx.y*64, c0 = blockIdx.x*64;   // r0 over t, c0 over d
  const int t = threadIdx.x, r = t>>3, cs = (t&7)*8;
  uint4 v = *(const uint4*)(in + (size_t)(r0+r)*4096 + c0 + cs);
  const u16* e = (const u16*)&v;
#pragma unroll
  for (int j=0;j<8;j++) tile[cs+j][r] = e[j];
  __syncthreads();
  uint4 o = *(const uint4*)&tile[r][cs];
  *(uint4*)(out + (size_t)(c0+r)*2048 + r0 + cs) = o;
}

// ---------------- RoPE, 8 pairs/thread; q rows pre-scaled by 1/sqrt(D)*log2(e) ----------------
__global__ __launch_bounds__(192) void rope8_k(u16* qkv, const float* __restrict__ fc,
                                               const float* __restrict__ fs){
  const int row = blockIdx.x;
  const int j = threadIdx.x;
  const int p0 = j*8;
  const int t = row & 2047;
  const int i0 = p0 & 63;
  uint4* ptr = (uint4*)(qkv + (size_t)row*4096 + p0*2);
  uint4 u0 = ptr[0], u1 = ptr[1];
  const float* fcp = fc + t*64 + i0;
  const float* fsp = fs + t*64 + i0;
  float4 c0 = *(const float4*)fcp, c1 = *(const float4*)(fcp+4);
  float4 s0 = *(const float4*)fsp, s1 = *(const float4*)(fsp+4);
  const float S2 = (p0 < 1024) ? (0.08838834764831845f * 1.4426950408889634f) : 1.0f;
  uint32_t wd[8] = {u0.x,u0.y,u0.z,u0.w,u1.x,u1.y,u1.z,u1.w};
  const float cc[8] = {c0.x,c0.y,c0.z,c0.w,c1.x,c1.y,c1.z,c1.w};
  const float ss[8] = {s0.x,s0.y,s0.z,s0.w,s1.x,s1.y,s1.z,s1.w};
#pragma unroll
  for (int k=0;k<8;k++){
    const float x0 = b2f((u16)(wd[k] & 0xffff));
    const float x1 = b2f((u16)(wd[k] >> 16));
    const float o0 = (x0*cc[k] - x1*ss[k]) * S2;
    const float o1 = (x0*ss[k] + x1*cc[k]) * S2;
    wd[k] = pk2(o0, o1);
  }
  u0 = make_uint4(wd[0],wd[1],wd[2],wd[3]);
  u1 = make_uint4(wd[4],wd[5],wd[6],wd[7]);
  ptr[0] = u0; ptr[1] = u1;
}

// ---------------- pipelined GEMM v1: BM=256, BN=128 (proj) ----------------
__global__ __launch_bounds__(512) void gemm_p(const u16* __restrict__ A, const u16* __restrict__ Bt,
                                              void* __restrict__ Cv, int M, int N, int K,
                                              const uint32_t* __restrict__ flag, int fin){
  __shared__ __align__(16) u16 L[3*12288];
  const int nwg_x = N>>7;
  int wg = blockIdx.x;
  { const int cpx = (int)gridDim.x >> 3; wg = (wg&7)*cpx + (wg>>3); }
  const int tm = (wg / nwg_x)*256, tn = (wg % nwg_x)*128;
  const int tid = threadIdx.x, w = tid>>6, l = tid&63, lr = l&15, lg = l>>4;
  const int wm = w>>1, wn = w&1;

  f32x4 acc[4][4] = {};

  auto stage = [&](int kt, int buf){
    const int kk = kt*32;
    u16* Lb = &L[buf*12288];
#pragma unroll
    for (int j=0;j<2;j++){
      const int s = j*512 + tid;
      const int row = s>>2, c = s&3;
      const int gch = c ^ ((row ^ (row>>2)) & 3);
      gload_lds16(A + (size_t)(tm + row)*K + kk + gch*8, &Lb[(j*512 + w*64)*8]);
    }
    {
      const int s = tid;
      const int row = s>>2, c = s&3;
      const int gch = c ^ ((row ^ (row>>2)) & 3);
      gload_lds16(Bt + (size_t)(tn + row)*K + kk + gch*8, &Lb[8192 + (w*64)*8]);
    }
  };

  const int nk = K>>5;
  stage(0,0); stage(1,1);
  asm volatile("s_waitcnt vmcnt(3)" ::: "memory");
  __builtin_amdgcn_s_barrier();
  __builtin_amdgcn_sched_barrier(0);

  for (int kt=0; kt<nk; ++kt){
    const int buf = kt % 3;
    if (kt+2 < nk) stage(kt+2, (kt+2) % 3);
    const u16* Ab = &L[buf*12288];
    const u16* Bb = Ab + 8192;
    bf16x8 a[4], b[4];
#pragma unroll
    for (int mi=0;mi<4;mi++){
      const int row = wm*64 + mi*16 + lr;
      a[mi] = *(const bf16x8*)&Ab[row*32 + ((lg ^ ((row ^ (row>>2))&3))*8)];
    }
#pragma unroll
    for (int ni=0;ni<4;ni++){
      const int row = wn*64 + ni*16 + lr;
      b[ni] = *(const bf16x8*)&Bb[row*32 + ((lg ^ ((row ^ (row>>2))&3))*8)];
    }
#pragma unroll
    for (int mi=0;mi<4;mi++)
#pragma unroll
      for (int ni=0;ni<4;ni++)
        acc[mi][ni] = __builtin_amdgcn_mfma_f32_16x16x32_bf16(a[mi], b[ni], acc[mi][ni], 0,0,0);
    __builtin_amdgcn_sched_barrier(0);
    if (kt+2 < nk) asm volatile("s_waitcnt vmcnt(3)" ::: "memory");
    else           asm volatile("s_waitcnt vmcnt(0)" ::: "memory");
    __builtin_amdgcn_s_barrier();
    __builtin_amdgcn_sched_barrier(0);
  }

  const bool of32 = fin && (flag[0] != 0);
#pragma unroll
  for (int mi=0;mi<4;mi++)
#pragma unroll
    for (int ni=0;ni<4;ni++)
#pragma unroll
      for (int reg=0;reg<4;reg++){
        const int row = tm + wm*64 + mi*16 + lg*4 + reg;
        const int col = tn + wn*64 + ni*16 + lr;
        const size_t idx = (size_t)row*N + col;
        const float v = acc[mi][ni][reg];
        if (of32) ((float*)Cv)[idx] = v;
        else      ((u16*)Cv)[idx]   = f2b(v);
      }
}

// ---------------- pipelined GEMM v2: BM=BN=256, per-wave 128x64 (qkv) ----------------
__global__ __launch_bounds__(512) void gemm_p2(const u16* __restrict__ A, const u16* __restrict__ Bt,
                                               void* __restrict__ Cv, int M, int N, int K,
                                               const uint32_t* __restrict__ flag, int fin){
  __shared__ __align__(16) u16 L[3*16384];
  const int nwg_x = N>>8;
  int wg = blockIdx.x;
  { const int cpx = (int)gridDim.x >> 3; wg = (wg&7)*cpx + (wg>>3); }
  const int tm = (wg / nwg_x)*256, tn = (wg % nwg_x)*256;
  const int tid = threadIdx.x, w = tid>>6, l = tid&63, lr = l&15, lg = l>>4;
  const int wm = w>>2, wn = w&3;

  f32x4 acc[8][4] = {};

  auto stage = [&](int kt, int buf){
    const int kk = kt*32;
    u16* Lb = &L[buf*16384];
#pragma unroll
    for (int j=0;j<2;j++){
      const int s = j*512 + tid;
      const int row = s>>2, c = s&3;
      const int gch = c ^ ((row ^ (row>>2)) & 3);
      gload_lds16(A + (size_t)(tm + row)*K + kk + gch*8, &Lb[(j*512 + w*64)*8]);
    }
#pragma unroll
    for (int j=0;j<2;j++){
      const int s = j*512 + tid;
      const int row = s>>2, c = s&3;
      const int gch = c ^ ((row ^ (row>>2)) & 3);
      gload_lds16(Bt + (size_t)(tn + row)*K + kk + gch*8, &Lb[8192 + (j*512 + w*64)*8]);
    }
  };

  const int nk = K>>5;
  stage(0,0); stage(1,1);
  asm volatile("s_waitcnt vmcnt(4)" ::: "memory");
  __builtin_amdgcn_s_barrier();
  __builtin_amdgcn_sched_barrier(0);

  for (int kt=0; kt<nk; ++kt){
    const int buf = kt % 3;
    if (kt+2 < nk) stage(kt+2, (kt+2) % 3);
    const u16* Ab = &L[buf*16384];
    const u16* Bb = Ab + 8192;
    bf16x8 a[8], b[4];
#pragma unroll
    for (int mi=0;mi<8;mi++){
      const int row = wm*128 + mi*16 + lr;
      a[mi] = *(const bf16x8*)&Ab[row*32 + ((lg ^ ((row ^ (row>>2))&3))*8)];
    }
#pragma unroll
    for (int ni=0;ni<4;ni++){
      const int row = wn*64 + ni*16 + lr;
      b[ni] = *(const bf16x8*)&Bb[row*32 + ((lg ^ ((row ^ (row>>2))&3))*8)];
    }
#pragma unroll
    for (int mi=0;mi<8;mi++)
#pragma unroll
      for (int ni=0;ni<4;ni++)
        acc[mi][ni] = __builtin_amdgcn_mfma_f32_16x16x32_bf16(a[mi], b[ni], acc[mi][ni], 0,0,0);
    __builtin_amdgcn_sched_barrier(0);
    if (kt+2 < nk) asm volatile("s_waitcnt vmcnt(4)" ::: "memory");
    else           asm volatile("s_waitcnt vmcnt(0)" ::: "memory");
    __builtin_amdgcn_s_barrier();
    __builtin_amdgcn_sched_barrier(0);
  }

  const bool of32 = fin && (flag[0] != 0);
#pragma unroll
  for (int mi=0;mi<8;mi++)
#pragma unroll
    for (int ni=0;ni<4;ni++)
#pragma unroll
      for (int reg=0;reg<4;reg++){
        const int row = tm + wm*128 + mi*16 + lg*4 + reg;
        const int col = tn + wn*64 + ni*16 + lr;
        const size_t idx = (size_t)row*N + col;
        const float v = acc[mi][ni][reg];
        if (of32) ((float*)Cv)[idx] = v;
        else      ((u16*)Cv)[idx]   = f2b(v);
      }
}

// ---------------- causal GQA flash attention v7 (R12-exact, ~109us) ----------------
__global__ __launch_bounds__(512, 1) void attn_k(const u16* __restrict__ qkv,
                                                 const u16* __restrict__ vT,
                                                 u16* __restrict__ y){
  __shared__ __align__(16) u16 KV[2][2][16384];
  const int i0 = blockIdx.x;
  const int g  = i0 & 7;
  const int r1 = i0 >> 3;
  const int hl = r1 & 1;
  const int vq = (r1 >> 1) & 7;
  const int b  = r1 >> 4;
  const int h  = g*2 + hl;

  const int tid = threadIdx.x;
  const int w = tid >> 6, l = tid & 63;
  const int grp = w >> 2, wq = w & 3;
  const int lq = l & 31;
  const int hi = l >> 5;

  const u16* kg = qkv + (size_t)(b*2048)*4096 + 2048 + g*128;
  const u16* vg = vT  + (size_t)(b*8+g)*128*2048;

  const int rk = tid >> 2, cb = tid & 3;
  uint4 kpre[4], vpre[4];
  auto loadT = [&](int kvbase){
#pragma unroll
    for (int j=0;j<4;j++){
      const int ch = cb + j*4;
      kpre[j] = *(const uint4*)(kg + (size_t)(kvbase + rk)*4096 + ch*8);
      vpre[j] = *(const uint4*)(vg + (size_t)rk*2048 + kvbase + ch*8);
    }
  };
  auto writeT = [&](int buf){
    u16* Kd = &KV[buf][rk>>6][0];
    const int rl = rk & 63;
#pragma unroll
    for (int j=0;j<4;j++){
      const int ch = cb + j*4;
      *(uint4*)&Kd[rl*128 + ((ch ^ (rl&15))*8)] = kpre[j];
    }
#pragma unroll
    for (int j=0;j<4;j++){
      const int ch = cb + j*4;
      u16* Vd = &KV[buf][ch>>3][8192];
      *(uint4*)&Vd[rk*64 + (((ch&7) ^ (rk&7))*8)] = vpre[j];
    }
  };

  int qt = vq;
  const int nA = vq + 1;
  bf16x8 qf[8];
  f32x16 yacc[4];
  float mrow, lsum;

  auto loadQ = [&]{
    const size_t qrow = (size_t)(b*2048 + qt*128 + wq*32 + lq);
    const u16* qp = qkv + qrow*4096 + h*128 + hi*8;
#pragma unroll
    for (int ds=0; ds<8; ++ds) qf[ds] = *(const bf16x8*)(qp + ds*16);
  };
  auto resetAcc = [&]{
#pragma unroll
    for (int dt=0; dt<4; ++dt)
#pragma unroll
      for (int r=0; r<16; ++r) yacc[dt][r] = 0.f;
    mrow = -1e30f; lsum = 0.f;
  };

  auto mergePhase = [&](u16* Mb){
    float* Mm = (float*)Mb; float* Ml = Mm + 128;
    u16* MOs = Mb + 512 + wq*4096;
    __syncthreads();
    if (grp == 1){
      if (l < 32){ Mm[wq*32 + l] = mrow; Ml[wq*32 + l] = lsum; }
#pragma unroll
      for (int dt=0; dt<4; ++dt)
#pragma unroll
        for (int rq=0; rq<4; ++rq){
          const int d0 = dt*32 + rq*8 + hi*4;
          uint32_t lo = pk2(yacc[dt][rq*4+0], yacc[dt][rq*4+1]);
          uint32_t hi2= pk2(yacc[dt][rq*4+2], yacc[dt][rq*4+3]);
          const int idx = (lq*128 + d0) ^ ((lq&7)<<3);
          *(uint2*)&MOs[idx] = make_uint2(lo, hi2);
        }
    }
    __syncthreads();
    if (grp == 0){
      const float mo = Mm[wq*32 + lq], lo_ = Ml[wq*32 + lq];
      const float ms = fmaxf(mrow, mo);
      const float ce = ex2(mrow - ms), co = ex2(mo - ms);
      const float inv = 1.f / (lsum*ce + lo_*co);
#pragma unroll
      for (int dt=0; dt<4; ++dt)
#pragma unroll
        for (int rq=0; rq<4; ++rq){
          const int d0 = dt*32 + rq*8 + hi*4;
          const int idx = (lq*128 + d0) ^ ((lq&7)<<3);
          uint2 pr = *(const uint2*)&MOs[idx];
          const float yo0 = b2f((u16)(pr.x & 0xffff)), yo1 = b2f((u16)(pr.x >> 16));
          const float yo2 = b2f((u16)(pr.y & 0xffff)), yo3 = b2f((u16)(pr.y >> 16));
          uint32_t lo = pk2((yacc[dt][rq*4+0]*ce + yo0*co)*inv, (yacc[dt][rq*4+1]*ce + yo1*co)*inv);
          uint32_t hi2= pk2((yacc[dt][rq*4+2]*ce + yo2*co)*inv, (yacc[dt][rq*4+3]*ce + yo3*co)*inv);
          *(uint2*)&MOs[idx] = make_uint2(lo, hi2);
        }
    }
    __syncthreads();
    const int qb2 = b*2048 + qt*128 + wq*32;
#pragma unroll
    for (int p=0; p<2; ++p){
      const int row = grp*16 + p*8 + (l>>3);
      const int gc = l & 7;
      const int idx0 = (row*128 + gc*16) ^ ((row&7)<<3);
      const int idx1 = (row*128 + gc*16 + 8) ^ ((row&7)<<3);
      uint4 v0 = *(const uint4*)&MOs[idx0];
      uint4 v1 = *(const uint4*)&MOs[idx1];
      u16* yp = y + (size_t)(qb2 + row)*2048 + h*128 + gc*16;
      *(uint4*)yp = v0;
      *(uint4*)(yp + 8) = v1;
    }
    __syncthreads();
  };

  loadT(0); writeT(0); __syncthreads();
  loadQ(); resetAcc();

  for (int s=0; s<17; ++s){
    if (s == nA){
      mergePhase(&KV[(nA&1)^1][0][0]);
      qt = 15 - vq;
      loadQ(); resetAcc();
    }
    const int sj = (s < nA) ? s : s - nA;
    const int kvbase = sj*128;
    if (s+1 < 17){
      const int s2 = s+1;
      const int sj2 = (s2 < nA) ? s2 : s2 - nA;
      loadT(sj2*128);
    }
    const u16* Kb = &KV[s&1][grp][0];
    const u16* Vb = Kb + 8192;
    const int tilebase = kvbase + grp*64;
    const int qmin = qt*128 + wq*32;
    const int qrow = qmin + lq;

    if (tilebase <= qmin + 31){
      f32x16 sc[2];
#pragma unroll
      for (int t=0;t<2;t++)
#pragma unroll
        for (int r=0;r<16;r++) sc[t][r] = 0.f;
      __builtin_amdgcn_s_setprio(1);
#pragma unroll
      for (int t=0; t<2; ++t){
        const int r = t*32 + lq;
        const int rsw = r & 15;
#pragma unroll
        for (int ds=0; ds<8; ++ds){
          const bf16x8 kf = *(const bf16x8*)&Kb[r*128 + (((2*ds+hi) ^ rsw)*8)];
          sc[t] = __builtin_amdgcn_mfma_f32_32x32x16_bf16(kf, qf[ds], sc[t], 0,0,0);
        }
      }
      __builtin_amdgcn_s_setprio(0);

      if (tilebase + 63 > qmin){
#pragma unroll
        for (int t=0;t<2;t++)
#pragma unroll
          for (int r=0;r<16;r++){
            const int kp = tilebase + t*32 + (r&3) + 8*(r>>2) + 4*hi;
            if (kp > qrow) sc[t][r] = -1e30f;
          }
      }

      float mx[16];
#pragma unroll
      for (int r=0;r<16;r++) mx[r] = fmaxf(sc[0][r], sc[1][r]);
#pragma unroll
      for (int off=8; off>0; off>>=1)
#pragma unroll
        for (int r=0;r<8;r++)
          if (r < off) mx[r] = fmaxf(mx[r], mx[r+off]);
      float pmax = fmaxf(mx[0], __shfl_xor(mx[0], 32));

      if (!__all(pmax <= mrow + 8.f)){
        const float mnew = fmaxf(mrow, pmax);
        const float corr = ex2(mrow - mnew);
        mrow = mnew; lsum *= corr;
#pragma unroll
        for (int dt=0;dt<4;dt++)
#pragma unroll
          for (int r=0;r<16;r++) yacc[dt][r] *= corr;
      }

#pragma unroll
      for (int t=0;t<2;t++)
#pragma unroll
        for (int r=0;r<16;r++) sc[t][r] = ex2(sc[t][r] - mrow);
      float sm[16];
#pragma unroll
      for (int r=0;r<16;r++) sm[r] = sc[0][r] + sc[1][r];
#pragma unroll
      for (int off=8; off>0; off>>=1)
#pragma unroll
        for (int r=0;r<8;r++)
          if (r < off) sm[r] += sm[r+off];
      lsum += sm[0] + __shfl_xor(sm[0], 32);

      __align__(16) uint32_t pw[4][4];
#pragma unroll
      for (int t=0;t<2;t++)
#pragma unroll
        for (int half=0; half<2; ++half){
          const int q8 = half*8;
          const uint32_t X0 = pk2(sc[t][q8+0], sc[t][q8+1]);
          const uint32_t X1 = pk2(sc[t][q8+2], sc[t][q8+3]);
          const uint32_t X2 = pk2(sc[t][q8+4], sc[t][q8+5]);
          const uint32_t X3 = pk2(sc[t][q8+6], sc[t][q8+7]);
          const uint32_t pX0 = (uint32_t)__shfl_xor((int)X0, 32);
          const uint32_t pX1 = (uint32_t)__shfl_xor((int)X1, 32);
          const uint32_t pX2 = (uint32_t)__shfl_xor((int)X2, 32);
          const uint32_t pX3 = (uint32_t)__shfl_xor((int)X3, 32);
          const int ks = t*2 + half;
          pw[ks][0] = hi ? pX2 : X0;
          pw[ks][1] = hi ? pX3 : X1;
          pw[ks][2] = hi ? X2 : pX0;
          pw[ks][3] = hi ? X3 : pX1;
        }

      __builtin_amdgcn_s_setprio(1);
#pragma unroll
      for (int dt=0; dt<4; ++dt){
        const int d = dt*32 + lq;
        const int dsw = d & 7;
#pragma unroll
        for (int ks=0; ks<4; ++ks){
          const bf16x8 vf = *(const bf16x8*)&Vb[d*64 + (((2*ks+hi) ^ dsw)*8)];
          yacc[dt] = __builtin_amdgcn_mfma_f32_32x32x16_bf16(vf, *(const bf16x8*)&pw[ks][0], yacc[dt], 0,0,0);
        }
      }
      __builtin_amdgcn_s_setprio(0);
    }

    if (s+1 < 17) writeT((s&1)^1);
    __syncthreads();
  }
  mergePhase(&KV[0][0][0]);
}

// ---------------- host ----------------
extern "C" void kernel_launch(void* const* d_in, const int* in_sizes, int n_in,
                              void* d_out, int out_size, void* d_ws, size_t ws_size,
                              hipStream_t stream){
  char* ws = (char*)d_ws;
  const size_t MB = 1048576;
  uint32_t* flag = (uint32_t*)(ws);
  float* fcF = (float*)(ws + 1*MB);
  float* fsF = (float*)(ws + 1*MB + 524288);
  u16* xb   = (u16*)(ws + 2*MB);           // 16 MB (reused as yb after gemm1)
  u16* waT  = (u16*)(ws + 18*MB);          // 16 MB
  u16* wpT  = (u16*)(ws + 34*MB);          // 8 MB
  u16* qkvb = (u16*)(ws + 42*MB);          // 32 MB
  u16* vTb  = (u16*)(ws + 74*MB);          // 8 MB
  u16* yb   = xb;

  detect_k<<<1, 64, 0, stream>>>((const uint32_t*)d_in[3], flag);
  cvtf2_k <<<1024, 256, 0, stream>>>(d_in[3], d_in[4], fcF, fsF, 131072, flag);
  cvtx_k  <<<4096, 256, 0, stream>>>(d_in[0], xb, 1048576, flag);
  wtrans_k<<<dim3(64,32,1), 512, 0, stream>>>(d_in[1], waT, 4096, 2048, flag);
  wtrans_k<<<dim3(32,32,1), 512, 0, stream>>>(d_in[2], wpT, 2048, 2048, flag);
  gemm_p2 <<<dim3(256,1,1), 512, 0, stream>>>(xb, waT, qkvb, 4096, 4096, 2048, flag, 0);
  rope8_k <<<dim3(4096,1,1), 192, 0, stream>>>(qkvb, fcF, fsF);
  vtrans_k<<<dim3(2,32,16), 512, 0, stream>>>(qkvb, vTb);
  attn_k  <<<dim3(256,1,1), 512, 0, stream>>>(qkvb, vTb, yb);
  gemm_p  <<<dim3(256,1,1), 512, 0, stream>>>(yb, wpT, d_out, 4096, 2048, 2048, flag, 1);
}